// Round 1
// baseline (285.735 us; speedup 1.0000x reference)
//
#include <hip/hip_runtime.h>
#include <math.h>

#define B 32
#define T 50
#define KK 10
#define NC 80
#define A_TOT 8400
#define EPSF 1e-7f
#define IOU_THR 0.1f

__device__ __forceinline__ float softplus_bce0(float x) {
    // BCEWithLogits(x, 0) = max(x,0) + log1p(exp(-|x|))
    return fmaxf(x, 0.0f) + log1pf(expf(-fabsf(x)));
}

__device__ __forceinline__ void decode_level(int a, int& aa, int& W, int& HW, float& s) {
    if (a < 6400)      { aa = a;        W = 80; HW = 6400; s = 8.0f;  }
    else if (a < 8000) { aa = a - 6400; W = 40; HW = 1600; s = 16.0f; }
    else               { aa = a - 8000; W = 20; HW = 400;  s = 32.0f; }
}

// ---------------------------------------------------------------------------
// Kernel 1: per (b,t), find 10 nearest anchor centers (jax.lax.top_k semantics:
// ascending distance, ties broken by lower anchor index).
// One wave per (b,t). Each lane keeps a sorted local top-10 in registers
// (constant indices only -> no scratch), then 10 rounds of wave-min merge.
// ---------------------------------------------------------------------------
__global__ __launch_bounds__(64) void topk_kernel(const float* __restrict__ targets,
                                                  int* __restrict__ idx_out) {
    int bt = blockIdx.x;              // b*T + t
    int lane = threadIdx.x;
    const float* tg = targets + bt * 5;
    float tcx = tg[0] + tg[2] * 0.5f;
    float tcy = tg[1] + tg[3] * 0.5f;

    float d[KK]; int id[KK];
#pragma unroll
    for (int p = 0; p < KK; ++p) { d[p] = INFINITY; id[p] = 0x7fffffff; }

    for (int a = lane; a < A_TOT; a += 64) {
        int aa, W, HW; float s;
        decode_level(a, aa, W, HW, s);
        int i = aa / W;
        int j = aa - i * W;
        float acx = j * s + s * 0.5f;
        float acy = i * s + s * 0.5f;
        float dx = acx - tcx, dy = acy - tcy;
        float dist = sqrtf(dx * dx + dy * dy);
        if (dist < d[KK - 1]) {           // strict: equal dist keeps lower idx
            d[KK - 1] = dist; id[KK - 1] = a;
#pragma unroll
            for (int p = KK - 1; p > 0; --p) {
                if (d[p] < d[p - 1]) {    // strict: stable for ties
                    float td = d[p]; d[p] = d[p - 1]; d[p - 1] = td;
                    int ti = id[p]; id[p] = id[p - 1]; id[p - 1] = ti;
                }
            }
        }
    }

    // merge 64 sorted lists: 10 rounds of wave-wide lexicographic min
    for (int k = 0; k < KK; ++k) {
        float cd = d[0]; int cid = id[0];
        float bd = cd;  int bid = cid;
#pragma unroll
        for (int sft = 1; sft < 64; sft <<= 1) {
            float od = __shfl_xor(bd, sft);
            int oid  = __shfl_xor(bid, sft);
            if (od < bd || (od == bd && oid < bid)) { bd = od; bid = oid; }
        }
        bool mine = (cd == bd && cid == bid);   // (d,id) unique -> one lane
        if (mine) {
#pragma unroll
            for (int p = 0; p < KK - 1; ++p) { d[p] = d[p + 1]; id[p] = id[p + 1]; }
            d[KK - 1] = INFINITY; id[KK - 1] = 0x7fffffff;
        }
        if (lane == 0) idx_out[bt * KK + k] = bid;
    }
}

// ---------------------------------------------------------------------------
// Kernel 2: per (b,t): decode pred boxes at the 10 selected anchors, IoU/CIoU,
// assignment mask (valid = iou>thr, else argmax fallback), accumulate
// reg_sum, cls_sum, num_pos; set per-anchor assigned flags for objectness.
// One wave per (b,t); lanes 0..9 own one k each; all 64 lanes cooperate on
// the 80-class BCE sum.
// ---------------------------------------------------------------------------
__global__ __launch_bounds__(64) void assign_kernel(
    const float* __restrict__ c3, const float* __restrict__ r3,
    const float* __restrict__ c4, const float* __restrict__ r4,
    const float* __restrict__ c5, const float* __restrict__ r5,
    const float* __restrict__ targets, const int* __restrict__ idx_in,
    unsigned char* __restrict__ flags, float* __restrict__ acc,
    unsigned int* __restrict__ npos)
{
    int bt = blockIdx.x;
    int b = bt / T;
    int lane = threadIdx.x;
    const float* tg = targets + bt * 5;
    float tw = tg[2], th = tg[3];
    float tcx = tg[0] + tw * 0.5f, tcy = tg[1] + th * 0.5f;
    int tcls = (int)tg[4];

    float x21 = tcx - tw * 0.5f, y21 = tcy - th * 0.5f;
    float x22 = tcx + tw * 0.5f, y22 = tcy + th * 0.5f;

    int a = 0;
    float iou = -INFINITY, ciou = 0.0f;
    bool valid = false;
    if (lane < KK) {
        a = idx_in[bt * KK + lane];
        int aa, W, HW; float s;
        decode_level(a, aa, W, HW, s);
        int i = aa / W, j = aa - i * W;
        const float* rb = (HW == 6400) ? r3 : (HW == 1600 ? r4 : r5);
        size_t rbase = ((size_t)b * 4) * (size_t)HW + (size_t)aa;
        float r0 = rb[rbase];
        float r1 = rb[rbase + (size_t)HW];
        float r2 = rb[rbase + 2 * (size_t)HW];
        float r3v = rb[rbase + 3 * (size_t)HW];
        float px = ((float)j + 1.0f / (1.0f + expf(-r0))) * s;
        float py = ((float)i + 1.0f / (1.0f + expf(-r1))) * s;
        float pw = expf(r2) * s;
        float ph = expf(r3v) * s;
        float x11 = px - pw * 0.5f, y11 = py - ph * 0.5f;
        float x12 = px + pw * 0.5f, y12 = py + ph * 0.5f;
        float iw = fmaxf(fminf(x12, x22) - fmaxf(x11, x21), 0.0f);
        float ih = fmaxf(fminf(y12, y22) - fmaxf(y11, y21), 0.0f);
        float inter = iw * ih;
        float a1 = (x12 - x11) * (y12 - y11);
        float a2 = (x22 - x21) * (y22 - y21);
        float uni = a1 + a2 - inter + EPSF;
        iou = inter / uni;
        valid = iou > IOU_THR;
        float cw = fmaxf(x12, x22) - fminf(x11, x21);
        float ch = fmaxf(y12, y22) - fminf(y11, y21);
        float c2 = cw * cw + ch * ch + EPSF;
        float ddx = x21 + x22 - x11 - x12;
        float ddy = y21 + y22 - y11 - y12;
        float rho2 = (ddx * ddx + ddy * ddy) * 0.25f;
        const float CPI = (float)(4.0 / (3.14159 * 3.14159));
        float dat = atanf((x22 - x21) / (y22 - y21 + EPSF))
                  - atanf((x12 - x11) / (y12 - y11 + EPSF));
        float v = CPI * dat * dat;
        float alpha = v / (1.0f - iou + v + EPSF);
        ciou = iou - (rho2 / c2 + v * alpha);
    }

    unsigned long long vmask = __ballot(valid);
    bool has_valid = (vmask != 0ull);

    // argmax over k of iou, first occurrence (lanes>=KK carry -inf)
    float bi = iou; int bl = lane;
#pragma unroll
    for (int sft = 1; sft < 64; sft <<= 1) {
        float oi = __shfl_xor(bi, sft);
        int ol  = __shfl_xor(bl, sft);
        if (oi > bi || (oi == bi && ol < bl)) { bi = oi; bl = ol; }
    }

    bool w = (lane < KK) && (has_valid ? valid : (lane == bl));
    unsigned long long wmask0 = __ballot(w);
    int npcount = __popcll(wmask0);

    // regression: sum (1 - ciou) over assigned
    float regc = w ? (1.0f - ciou) : 0.0f;
#pragma unroll
    for (int sft = 1; sft < 64; sft <<= 1) regc += __shfl_xor(regc, sft);

    // objectness flags (idempotent byte stores; duplicates across targets ok)
    if (w) flags[b * A_TOT + a] = 1;

    // classification: sum_c bce(cls_c, onehot) = sum_c softplus(cls_c) - cls_true
    float csum = 0.0f;
    unsigned long long wmask = wmask0;       // wave-uniform
    while (wmask) {
        int k = __ffsll((unsigned long long)wmask) - 1;
        wmask &= wmask - 1;
        int ak = __shfl(a, k);
        int aak, Wk, HWk; float sk;
        decode_level(ak, aak, Wk, HWk, sk);
        const float* cb = (HWk == 6400) ? c3 : (HWk == 1600 ? c4 : c5);
        size_t cbase = ((size_t)b * NC) * (size_t)HWk + (size_t)aak;
        csum += softplus_bce0(cb[cbase + (size_t)lane * HWk]);
        if (lane < NC - 64)
            csum += softplus_bce0(cb[cbase + (size_t)(64 + lane) * HWk]);
        if (lane == 0)
            csum -= cb[cbase + (size_t)tcls * HWk];
    }
#pragma unroll
    for (int sft = 1; sft < 64; sft <<= 1) csum += __shfl_xor(csum, sft);

    if (lane == 0) {
        atomicAdd(&acc[0], regc);
        atomicAdd(&acc[1], csum);
        atomicAdd(npos, (unsigned int)npcount);
    }
}

// ---------------------------------------------------------------------------
// Kernel 3: objectness. obj_sum = sum_all softplus(x) - sum_{assigned} x
// ---------------------------------------------------------------------------
__global__ __launch_bounds__(256) void obj_kernel(
    const float* __restrict__ o3, const float* __restrict__ o4,
    const float* __restrict__ o5, const unsigned char* __restrict__ flags,
    float* __restrict__ acc)
{
    int n = blockIdx.x * blockDim.x + threadIdx.x;
    float local = 0.0f;
    if (n < B * A_TOT) {
        int b = n / A_TOT;
        int a = n - b * A_TOT;
        int aa, W, HW; float s;
        decode_level(a, aa, W, HW, s);
        const float* ob = (HW == 6400) ? o3 : (HW == 1600 ? o4 : o5);
        float x = ob[(size_t)b * HW + aa];
        local = softplus_bce0(x) - (flags[n] ? x : 0.0f);
    }
#pragma unroll
    for (int sft = 1; sft < 64; sft <<= 1) local += __shfl_xor(local, sft);
    if ((threadIdx.x & 63) == 0) atomicAdd(&acc[2], local);
}

// ---------------------------------------------------------------------------
// Kernel 4: finalize -> [total, reg_l, obj_l, cls_l]
// ---------------------------------------------------------------------------
__global__ void finalize_kernel(const float* __restrict__ acc,
                                const unsigned int* __restrict__ npos,
                                float* __restrict__ out)
{
    if (threadIdx.x == 0 && blockIdx.x == 0) {
        float np = fmaxf((float)(*npos), 1.0f);
        float reg_l = acc[0] / np;
        float cls_l = acc[1] / np;
        float obj_l = acc[2] / np;
        out[0] = 5.0f * reg_l + obj_l + cls_l;
        out[1] = reg_l;
        out[2] = obj_l;
        out[3] = cls_l;
    }
}

extern "C" void kernel_launch(void* const* d_in, const int* in_sizes, int n_in,
                              void* d_out, int out_size, void* d_ws, size_t ws_size,
                              hipStream_t stream) {
    const float* p3c = (const float*)d_in[0];
    const float* p3r = (const float*)d_in[1];
    const float* p3o = (const float*)d_in[2];
    const float* p4c = (const float*)d_in[3];
    const float* p4r = (const float*)d_in[4];
    const float* p4o = (const float*)d_in[5];
    const float* p5c = (const float*)d_in[6];
    const float* p5r = (const float*)d_in[7];
    const float* p5o = (const float*)d_in[8];
    const float* targets = (const float*)d_in[9];

    char* ws = (char*)d_ws;
    float* acc = (float*)ws;                                 // [reg, cls, obj]
    unsigned int* npos = (unsigned int*)(ws + 12);
    unsigned char* flags = (unsigned char*)(ws + 16);        // B*A bytes
    int* idx = (int*)(ws + 16 + B * A_TOT);                  // B*T*K ints

    hipMemsetAsync(d_ws, 0, 16 + B * A_TOT, stream);

    topk_kernel<<<B * T, 64, 0, stream>>>(targets, idx);
    assign_kernel<<<B * T, 64, 0, stream>>>(p3c, p3r, p4c, p4r, p5c, p5r,
                                            targets, idx, flags, acc, npos);
    obj_kernel<<<(B * A_TOT + 255) / 256, 256, 0, stream>>>(p3o, p4o, p5o, flags, acc);
    finalize_kernel<<<1, 64, 0, stream>>>(acc, npos, (float*)d_out);
}

// Round 2
// 176.422 us; speedup vs baseline: 1.6196x; 1.6196x over previous
//
#include <hip/hip_runtime.h>
#include <math.h>

#define B 32
#define T 50
#define KK 10
#define NC 80
#define A_TOT 8400
#define EPSF 1e-7f
#define IOU_THR 0.1f

__device__ __forceinline__ float softplus_bce0(float x) {
    // BCEWithLogits(x, 0) = max(x,0) + log1p(exp(-|x|))
    return fmaxf(x, 0.0f) + log1pf(expf(-fabsf(x)));
}

__device__ __forceinline__ void decode_level(int a, int& aa, int& W, int& HW, float& s) {
    if (a < 6400)      { aa = a;        W = 80; HW = 6400; s = 8.0f;  }
    else if (a < 8000) { aa = a - 6400; W = 40; HW = 1600; s = 16.0f; }
    else               { aa = a - 8000; W = 20; HW = 400;  s = 32.0f; }
}

__device__ __forceinline__ void topk_insert(float (&d)[KK], int (&id)[KK],
                                            float dist, int a) {
    if (dist < d[KK - 1]) {               // strict: equal dist keeps lower idx
        d[KK - 1] = dist; id[KK - 1] = a;
#pragma unroll
        for (int p = KK - 1; p > 0; --p) {
            if (d[p] < d[p - 1]) {        // strict: stable for ties
                float td = d[p]; d[p] = d[p - 1]; d[p - 1] = td;
                int ti = id[p]; id[p] = id[p - 1]; id[p - 1] = ti;
            }
        }
    }
}

// ---------------------------------------------------------------------------
// Fused kernel: per (b,t) wave: top-10 nearest anchors (jax.lax.top_k
// semantics), then decode/IoU/CIoU/assignment/cls-BCE. Writes per-block
// partials (no contended atomics) + per-anchor assigned flags.
// ---------------------------------------------------------------------------
__global__ __launch_bounds__(64) void fused_kernel(
    const float* __restrict__ c3, const float* __restrict__ r3,
    const float* __restrict__ c4, const float* __restrict__ r4,
    const float* __restrict__ c5, const float* __restrict__ r5,
    const float* __restrict__ targets,
    unsigned char* __restrict__ flags, float4* __restrict__ partials)
{
    int bt = blockIdx.x;              // b*T + t
    int b = bt / T;
    int lane = threadIdx.x;
    const float* tg = targets + bt * 5;
    float tw = tg[2], th = tg[3];
    float tcx = tg[0] + tw * 0.5f, tcy = tg[1] + th * 0.5f;
    int tcls = (int)tg[4];

    // ---------------- top-k ----------------
    float d[KK]; int id[KK];
#pragma unroll
    for (int p = 0; p < KK; ++p) { d[p] = INFINITY; id[p] = 0x7fffffff; }

    // level P3: a in [0,6400), W=80, s=8
    for (int a = lane; a < 6400; a += 64) {
        int i = a / 80, j = a - i * 80;
        float dx = j * 8.0f + 4.0f - tcx, dy = i * 8.0f + 4.0f - tcy;
        topk_insert(d, id, sqrtf(dx * dx + dy * dy), a);
    }
    // level P4: a in [6400,8000), W=40, s=16
    for (int a = 6400 + lane; a < 8000; a += 64) {
        int aa = a - 6400;
        int i = aa / 40, j = aa - i * 40;
        float dx = j * 16.0f + 8.0f - tcx, dy = i * 16.0f + 8.0f - tcy;
        topk_insert(d, id, sqrtf(dx * dx + dy * dy), a);
    }
    // level P5: a in [8000,8400), W=20, s=32
    for (int a = 8000 + lane; a < 8400; a += 64) {
        int aa = a - 8000;
        int i = aa / 20, j = aa - i * 20;
        float dx = j * 32.0f + 16.0f - tcx, dy = i * 32.0f + 16.0f - tcy;
        topk_insert(d, id, sqrtf(dx * dx + dy * dy), a);
    }

    // merge 64 sorted lists: 10 rounds of wave-wide lexicographic min;
    // lane k keeps the k-th selected anchor in `a`.
    int a = 0;
    for (int k = 0; k < KK; ++k) {
        float cd = d[0]; int cid = id[0];
        float bd = cd;  int bid = cid;
#pragma unroll
        for (int sft = 1; sft < 64; sft <<= 1) {
            float od = __shfl_xor(bd, sft);
            int oid  = __shfl_xor(bid, sft);
            if (od < bd || (od == bd && oid < bid)) { bd = od; bid = oid; }
        }
        bool mine = (cd == bd && cid == bid);   // anchor ids unique -> one lane
        if (mine) {
#pragma unroll
            for (int p = 0; p < KK - 1; ++p) { d[p] = d[p + 1]; id[p] = id[p + 1]; }
            d[KK - 1] = INFINITY; id[KK - 1] = 0x7fffffff;
        }
        if (lane == k) a = bid;
    }

    // ---------------- assignment / losses ----------------
    float x21 = tcx - tw * 0.5f, y21 = tcy - th * 0.5f;
    float x22 = tcx + tw * 0.5f, y22 = tcy + th * 0.5f;

    float iou = -INFINITY, ciou = 0.0f;
    bool valid = false;
    if (lane < KK) {
        int aa, W, HW; float s;
        decode_level(a, aa, W, HW, s);
        int i = aa / W, j = aa - i * W;
        const float* rb = (HW == 6400) ? r3 : (HW == 1600 ? r4 : r5);
        size_t rbase = ((size_t)b * 4) * (size_t)HW + (size_t)aa;
        float r0 = rb[rbase];
        float r1 = rb[rbase + (size_t)HW];
        float r2 = rb[rbase + 2 * (size_t)HW];
        float r3v = rb[rbase + 3 * (size_t)HW];
        float px = ((float)j + 1.0f / (1.0f + expf(-r0))) * s;
        float py = ((float)i + 1.0f / (1.0f + expf(-r1))) * s;
        float pw = expf(r2) * s;
        float ph = expf(r3v) * s;
        float x11 = px - pw * 0.5f, y11 = py - ph * 0.5f;
        float x12 = px + pw * 0.5f, y12 = py + ph * 0.5f;
        float iw = fmaxf(fminf(x12, x22) - fmaxf(x11, x21), 0.0f);
        float ih = fmaxf(fminf(y12, y22) - fmaxf(y11, y21), 0.0f);
        float inter = iw * ih;
        float a1 = (x12 - x11) * (y12 - y11);
        float a2 = (x22 - x21) * (y22 - y21);
        float uni = a1 + a2 - inter + EPSF;
        iou = inter / uni;
        valid = iou > IOU_THR;
        float cw = fmaxf(x12, x22) - fminf(x11, x21);
        float ch = fmaxf(y12, y22) - fminf(y11, y21);
        float c2 = cw * cw + ch * ch + EPSF;
        float ddx = x21 + x22 - x11 - x12;
        float ddy = y21 + y22 - y11 - y12;
        float rho2 = (ddx * ddx + ddy * ddy) * 0.25f;
        const float CPI = (float)(4.0 / (3.14159 * 3.14159));
        float dat = atanf((x22 - x21) / (y22 - y21 + EPSF))
                  - atanf((x12 - x11) / (y12 - y11 + EPSF));
        float v = CPI * dat * dat;
        float alpha = v / (1.0f - iou + v + EPSF);
        ciou = iou - (rho2 / c2 + v * alpha);
    }

    unsigned long long vmask = __ballot(valid);
    bool has_valid = (vmask != 0ull);

    // argmax over k of iou, first occurrence (lanes>=KK carry -inf)
    float bi = iou; int bl = lane;
#pragma unroll
    for (int sft = 1; sft < 64; sft <<= 1) {
        float oi = __shfl_xor(bi, sft);
        int ol  = __shfl_xor(bl, sft);
        if (oi > bi || (oi == bi && ol < bl)) { bi = oi; bl = ol; }
    }

    bool w = (lane < KK) && (has_valid ? valid : (lane == bl));
    unsigned long long wmask0 = __ballot(w);
    int npcount = __popcll(wmask0);

    // regression: sum (1 - ciou) over assigned
    float regc = w ? (1.0f - ciou) : 0.0f;
#pragma unroll
    for (int sft = 1; sft < 64; sft <<= 1) regc += __shfl_xor(regc, sft);

    // objectness flags (idempotent byte stores; duplicates across targets ok)
    if (w) flags[b * A_TOT + a] = 1;

    // classification: sum_c bce(cls_c, onehot) = sum_c softplus(cls_c) - cls_true
    float csum = 0.0f;
    unsigned long long wmask = wmask0;       // wave-uniform
    while (wmask) {
        int k = __ffsll((unsigned long long)wmask) - 1;
        wmask &= wmask - 1;
        int ak = __shfl(a, k);
        int aak, Wk, HWk; float sk;
        decode_level(ak, aak, Wk, HWk, sk);
        const float* cb = (HWk == 6400) ? c3 : (HWk == 1600 ? c4 : c5);
        size_t cbase = ((size_t)b * NC) * (size_t)HWk + (size_t)aak;
        csum += softplus_bce0(cb[cbase + (size_t)lane * HWk]);
        if (lane < NC - 64)
            csum += softplus_bce0(cb[cbase + (size_t)(64 + lane) * HWk]);
        if (lane == 0)
            csum -= cb[cbase + (size_t)tcls * HWk];
    }
#pragma unroll
    for (int sft = 1; sft < 64; sft <<= 1) csum += __shfl_xor(csum, sft);

    if (lane == 0)
        partials[bt] = make_float4(regc, csum, (float)npcount, 0.0f);
}

// ---------------------------------------------------------------------------
// Objectness: obj_sum = sum_all softplus(x) - sum_{assigned} x
// 256 blocks x 256 threads, grid-stride; block-reduced partial per block.
// ---------------------------------------------------------------------------
#define OBJ_BLOCKS 256
__global__ __launch_bounds__(256) void obj_kernel(
    const float* __restrict__ o3, const float* __restrict__ o4,
    const float* __restrict__ o5, const unsigned char* __restrict__ flags,
    float* __restrict__ part_obj)
{
    int tid = blockIdx.x * 256 + threadIdx.x;
    const int stride = OBJ_BLOCKS * 256;
    float local = 0.0f;
    for (int n = tid; n < B * 6400; n += stride) {
        int b = n / 6400, aa = n - b * 6400;
        float x = o3[n];
        local += softplus_bce0(x) - (flags[b * A_TOT + aa] ? x : 0.0f);
    }
    for (int n = tid; n < B * 1600; n += stride) {
        int b = n / 1600, aa = n - b * 1600;
        float x = o4[n];
        local += softplus_bce0(x) - (flags[b * A_TOT + 6400 + aa] ? x : 0.0f);
    }
    for (int n = tid; n < B * 400; n += stride) {
        int b = n / 400, aa = n - b * 400;
        float x = o5[n];
        local += softplus_bce0(x) - (flags[b * A_TOT + 8000 + aa] ? x : 0.0f);
    }
#pragma unroll
    for (int sft = 1; sft < 64; sft <<= 1) local += __shfl_xor(local, sft);
    __shared__ float sred[4];
    if ((threadIdx.x & 63) == 0) sred[threadIdx.x >> 6] = local;
    __syncthreads();
    if (threadIdx.x == 0)
        part_obj[blockIdx.x] = sred[0] + sred[1] + sred[2] + sred[3];
}

// ---------------------------------------------------------------------------
// Finalize: reduce 1600 float4 partials + 256 obj partials -> 4 outputs.
// ---------------------------------------------------------------------------
__global__ __launch_bounds__(256) void finalize_kernel(
    const float4* __restrict__ partials, const float* __restrict__ part_obj,
    float* __restrict__ out)
{
    int tid = threadIdx.x;
    float reg = 0.0f, cls = 0.0f, np = 0.0f, obj = part_obj[tid];
    for (int i = tid; i < B * T; i += 256) {
        float4 p = partials[i];
        reg += p.x; cls += p.y; np += p.z;
    }
#pragma unroll
    for (int sft = 1; sft < 64; sft <<= 1) {
        reg += __shfl_xor(reg, sft);
        cls += __shfl_xor(cls, sft);
        np  += __shfl_xor(np, sft);
        obj += __shfl_xor(obj, sft);
    }
    __shared__ float sred[4][4];
    int wv = tid >> 6;
    if ((tid & 63) == 0) {
        sred[wv][0] = reg; sred[wv][1] = cls; sred[wv][2] = np; sred[wv][3] = obj;
    }
    __syncthreads();
    if (tid == 0) {
        float R = 0, C = 0, N = 0, O = 0;
        for (int i = 0; i < 4; ++i) {
            R += sred[i][0]; C += sred[i][1]; N += sred[i][2]; O += sred[i][3];
        }
        float npf = fmaxf(N, 1.0f);
        float reg_l = R / npf, cls_l = C / npf, obj_l = O / npf;
        out[0] = 5.0f * reg_l + obj_l + cls_l;
        out[1] = reg_l;
        out[2] = obj_l;
        out[3] = cls_l;
    }
}

extern "C" void kernel_launch(void* const* d_in, const int* in_sizes, int n_in,
                              void* d_out, int out_size, void* d_ws, size_t ws_size,
                              hipStream_t stream) {
    const float* p3c = (const float*)d_in[0];
    const float* p3r = (const float*)d_in[1];
    const float* p3o = (const float*)d_in[2];
    const float* p4c = (const float*)d_in[3];
    const float* p4r = (const float*)d_in[4];
    const float* p4o = (const float*)d_in[5];
    const float* p5c = (const float*)d_in[6];
    const float* p5r = (const float*)d_in[7];
    const float* p5o = (const float*)d_in[8];
    const float* targets = (const float*)d_in[9];

    char* ws = (char*)d_ws;
    unsigned char* flags = (unsigned char*)ws;                    // B*A bytes
    float4* partials = (float4*)(ws + B * A_TOT);                 // 1600 float4
    float* part_obj = (float*)(ws + B * A_TOT + B * T * 16);      // 256 floats

    hipMemsetAsync(flags, 0, B * A_TOT, stream);

    fused_kernel<<<B * T, 64, 0, stream>>>(p3c, p3r, p4c, p4r, p5c, p5r,
                                           targets, flags, partials);
    obj_kernel<<<OBJ_BLOCKS, 256, 0, stream>>>(p3o, p4o, p5o, flags, part_obj);
    finalize_kernel<<<1, 256, 0, stream>>>(partials, part_obj, (float*)d_out);
}

// Round 3
// 148.583 us; speedup vs baseline: 1.9231x; 1.1874x over previous
//
#include <hip/hip_runtime.h>
#include <math.h>

#define B 32
#define T 50
#define KK 10
#define NC 80
#define A_TOT 8400
#define EPSF 1e-7f
#define IOU_THR 0.1f

#define WORDS_PER_B 264           // ceil(8400/32)=263, padded to 264
#define BITS_BYTES (B * WORDS_PER_B * 4)

__device__ __forceinline__ float softplus_bce0(float x) {
    // BCEWithLogits(x, 0) = max(x,0) + log1p(exp(-|x|))
    return fmaxf(x, 0.0f) + log1pf(expf(-fabsf(x)));
}

__device__ __forceinline__ void decode_level(int a, int& aa, int& W, int& HW, float& s) {
    if (a < 6400)      { aa = a;        W = 80; HW = 6400; s = 8.0f;  }
    else if (a < 8000) { aa = a - 6400; W = 40; HW = 1600; s = 16.0f; }
    else               { aa = a - 8000; W = 20; HW = 400;  s = 32.0f; }
}

__device__ __forceinline__ void csw(float& da, int& ia, float& db, int& ib) {
    // compare-swap ascending by (dist, idx)
    if (db < da || (db == da && ib < ia)) {
        float td = da; da = db; db = td;
        int ti = ia; ia = ib; ib = ti;
    }
}

// ---------------------------------------------------------------------------
// Fused kernel, one wave per (b,t):
//  1. top-10 nearest anchors via clamped 8x8 windows per level (1 cell/lane/
//     level -> 3 candidates/lane, provable superset of the true top-10),
//     exact lexicographic (dist, idx) wave merge = jax.lax.top_k semantics.
//  2. decode/IoU/CIoU/assignment, cls BCE (unrolled 10, weight-multiplied).
//  3. objectness: dense softplus over this block's slice + exactly-once
//     subtraction of assigned-anchor logits via atomicOr bit dedupe.
//  Writes one float4 partial per block; no contended atomics.
// ---------------------------------------------------------------------------
__global__ __launch_bounds__(64) void fused_kernel(
    const float* __restrict__ c3, const float* __restrict__ r3,
    const float* __restrict__ c4, const float* __restrict__ r4,
    const float* __restrict__ c5, const float* __restrict__ r5,
    const float* __restrict__ o3, const float* __restrict__ o4,
    const float* __restrict__ o5, const float* __restrict__ targets,
    unsigned int* __restrict__ bits, float4* __restrict__ partials)
{
    int bt = blockIdx.x;              // b*T + t
    int b = bt / T;
    int lane = threadIdx.x;
    const float* tg = targets + bt * 5;
    float tw = tg[2], th = tg[3];
    float tcx = tg[0] + tw * 0.5f, tcy = tg[1] + th * 0.5f;
    int tcls = (int)tg[4];

    // ---------------- top-k via 8x8 windows ----------------
    int ci = lane & 7, ri = lane >> 3;

    float d0, d1, d2; int id0, id1, id2;
    {
        // P3: s=8, 80x80
        int j0 = (int)(tcx * 0.125f), i0 = (int)(tcy * 0.125f);
        int js = min(max(j0 - 3, 0), 72), is = min(max(i0 - 3, 0), 72);
        int j = js + ci, i = is + ri;
        float dx = j * 8.0f + 4.0f - tcx, dy = i * 8.0f + 4.0f - tcy;
        d0 = sqrtf(dx * dx + dy * dy); id0 = i * 80 + j;
    }
    {
        // P4: s=16, 40x40
        int j0 = (int)(tcx * 0.0625f), i0 = (int)(tcy * 0.0625f);
        int js = min(max(j0 - 3, 0), 32), is = min(max(i0 - 3, 0), 32);
        int j = js + ci, i = is + ri;
        float dx = j * 16.0f + 8.0f - tcx, dy = i * 16.0f + 8.0f - tcy;
        d1 = sqrtf(dx * dx + dy * dy); id1 = 6400 + i * 40 + j;
    }
    {
        // P5: s=32, 20x20
        int j0 = (int)(tcx * 0.03125f), i0 = (int)(tcy * 0.03125f);
        int js = min(max(j0 - 3, 0), 12), is = min(max(i0 - 3, 0), 12);
        int j = js + ci, i = is + ri;
        float dx = j * 32.0f + 16.0f - tcx, dy = i * 32.0f + 16.0f - tcy;
        d2 = sqrtf(dx * dx + dy * dy); id2 = 8000 + i * 20 + j;
    }
    // sort the lane's 3 candidates ascending (network: (0,1)(1,2)(0,1))
    csw(d0, id0, d1, id1);
    csw(d1, id1, d2, id2);
    csw(d0, id0, d1, id1);

    // merge: 10 rounds of wave-wide lexicographic min over lane heads;
    // lane k keeps the k-th selected anchor in `a`. Anchor ids are unique.
    int a = 0;
    for (int k = 0; k < KK; ++k) {
        float bd = d0; int bid = id0;
#pragma unroll
        for (int sft = 1; sft < 64; sft <<= 1) {
            float od = __shfl_xor(bd, sft);
            int oid  = __shfl_xor(bid, sft);
            if (od < bd || (od == bd && oid < bid)) { bd = od; bid = oid; }
        }
        if (d0 == bd && id0 == bid) {   // exactly one lane (ids unique)
            d0 = d1; id0 = id1;
            d1 = d2; id1 = id2;
            d2 = INFINITY; id2 = 0x7fffffff;
        }
        if (lane == k) a = bid;
    }

    // ---------------- assignment / CIoU ----------------
    float x21 = tcx - tw * 0.5f, y21 = tcy - th * 0.5f;
    float x22 = tcx + tw * 0.5f, y22 = tcy + th * 0.5f;

    float iou = -INFINITY, ciou = 0.0f;
    bool valid = false;
    if (lane < KK) {
        int aa, W, HW; float s;
        decode_level(a, aa, W, HW, s);
        int i = aa / W, j = aa - i * W;
        const float* rb = (HW == 6400) ? r3 : (HW == 1600 ? r4 : r5);
        size_t rbase = ((size_t)b * 4) * (size_t)HW + (size_t)aa;
        float r0 = rb[rbase];
        float r1 = rb[rbase + (size_t)HW];
        float r2 = rb[rbase + 2 * (size_t)HW];
        float r3v = rb[rbase + 3 * (size_t)HW];
        float px = ((float)j + 1.0f / (1.0f + expf(-r0))) * s;
        float py = ((float)i + 1.0f / (1.0f + expf(-r1))) * s;
        float pw = expf(r2) * s;
        float ph = expf(r3v) * s;
        float x11 = px - pw * 0.5f, y11 = py - ph * 0.5f;
        float x12 = px + pw * 0.5f, y12 = py + ph * 0.5f;
        float iw = fmaxf(fminf(x12, x22) - fmaxf(x11, x21), 0.0f);
        float ih = fmaxf(fminf(y12, y22) - fmaxf(y11, y21), 0.0f);
        float inter = iw * ih;
        float a1 = (x12 - x11) * (y12 - y11);
        float a2 = (x22 - x21) * (y22 - y21);
        float uni = a1 + a2 - inter + EPSF;
        iou = inter / uni;
        valid = iou > IOU_THR;
        float cw = fmaxf(x12, x22) - fminf(x11, x21);
        float ch = fmaxf(y12, y22) - fminf(y11, y21);
        float c2 = cw * cw + ch * ch + EPSF;
        float ddx = x21 + x22 - x11 - x12;
        float ddy = y21 + y22 - y11 - y12;
        float rho2 = (ddx * ddx + ddy * ddy) * 0.25f;
        const float CPI = (float)(4.0 / (3.14159 * 3.14159));
        float dat = atanf((x22 - x21) / (y22 - y21 + EPSF))
                  - atanf((x12 - x11) / (y12 - y11 + EPSF));
        float v = CPI * dat * dat;
        float alpha = v / (1.0f - iou + v + EPSF);
        ciou = iou - (rho2 / c2 + v * alpha);
    }

    unsigned long long vmask = __ballot(valid);
    bool has_valid = (vmask != 0ull);

    // argmax over k of iou, first occurrence (lanes>=KK carry -inf)
    float bi = iou; int bl = lane;
#pragma unroll
    for (int sft = 1; sft < 64; sft <<= 1) {
        float oi = __shfl_xor(bi, sft);
        int ol  = __shfl_xor(bl, sft);
        if (oi > bi || (oi == bi && ol < bl)) { bi = oi; bl = ol; }
    }

    bool w = (lane < KK) && (has_valid ? valid : (lane == bl));
    unsigned long long wmask0 = __ballot(w);
    int npcount = __popcll(wmask0);

    // regression: sum (1 - ciou) over assigned
    float regc = w ? (1.0f - ciou) : 0.0f;
#pragma unroll
    for (int sft = 1; sft < 64; sft <<= 1) regc += __shfl_xor(regc, sft);

    // ---------------- objectness ----------------
    // obj_sum = sum_all softplus(x) - sum_{distinct assigned} x
    float osum = 0.0f;
    {
        int gt = bt * 64 + lane;               // 102400 threads total
        osum += softplus_bce0(o3[gt]);         // B*6400 = 204800
        osum += softplus_bce0(o3[gt + 102400]);
        if (gt < 51200) osum += softplus_bce0(o4[gt]);   // B*1600
        if (gt < 12800) osum += softplus_bce0(o5[gt]);   // B*400
    }
    if (w) {
        unsigned int bit = 1u << (a & 31);
        unsigned int old = atomicOr(&bits[b * WORDS_PER_B + (a >> 5)], bit);
        if (!(old & bit)) {                    // exactly-once per (b, anchor)
            int aa, W, HW; float s;
            decode_level(a, aa, W, HW, s);
            const float* ob = (HW == 6400) ? o3 : (HW == 1600 ? o4 : o5);
            osum -= ob[(size_t)b * HW + aa];
        }
    }
#pragma unroll
    for (int sft = 1; sft < 64; sft <<= 1) osum += __shfl_xor(osum, sft);

    // ---------------- classification ----------------
    // sum_c bce(x_c, onehot) = sum_c softplus(x_c) - x_true; unrolled over
    // all 10 k (always-valid anchor ids), weighted by assignment.
    float csum = 0.0f;
#pragma unroll
    for (int k = 0; k < KK; ++k) {
        float wk = ((wmask0 >> k) & 1ull) ? 1.0f : 0.0f;   // wave-uniform
        int ak = __shfl(a, k);
        int aak, Wk, HWk; float sk;
        decode_level(ak, aak, Wk, HWk, sk);
        const float* cb = (HWk == 6400) ? c3 : (HWk == 1600 ? c4 : c5);
        size_t cbase = ((size_t)b * NC) * (size_t)HWk + (size_t)aak;
        float contrib = softplus_bce0(cb[cbase + (size_t)lane * HWk]);
        if (lane < NC - 64)
            contrib += softplus_bce0(cb[cbase + (size_t)(64 + lane) * HWk]);
        if (lane == 0)
            contrib -= cb[cbase + (size_t)tcls * HWk];
        csum += wk * contrib;
    }
#pragma unroll
    for (int sft = 1; sft < 64; sft <<= 1) csum += __shfl_xor(csum, sft);

    if (lane == 0)
        partials[bt] = make_float4(regc, csum, (float)npcount, osum);
}

// ---------------------------------------------------------------------------
// Finalize: reduce 1600 float4 partials -> [total, reg_l, obj_l, cls_l]
// ---------------------------------------------------------------------------
__global__ __launch_bounds__(256) void finalize_kernel(
    const float4* __restrict__ partials, float* __restrict__ out)
{
    int tid = threadIdx.x;
    float reg = 0.0f, cls = 0.0f, np = 0.0f, obj = 0.0f;
    for (int i = tid; i < B * T; i += 256) {
        float4 p = partials[i];
        reg += p.x; cls += p.y; np += p.z; obj += p.w;
    }
#pragma unroll
    for (int sft = 1; sft < 64; sft <<= 1) {
        reg += __shfl_xor(reg, sft);
        cls += __shfl_xor(cls, sft);
        np  += __shfl_xor(np, sft);
        obj += __shfl_xor(obj, sft);
    }
    __shared__ float sred[4][4];
    int wv = tid >> 6;
    if ((tid & 63) == 0) {
        sred[wv][0] = reg; sred[wv][1] = cls; sred[wv][2] = np; sred[wv][3] = obj;
    }
    __syncthreads();
    if (tid == 0) {
        float R = 0, C = 0, N = 0, O = 0;
        for (int i = 0; i < 4; ++i) {
            R += sred[i][0]; C += sred[i][1]; N += sred[i][2]; O += sred[i][3];
        }
        float npf = fmaxf(N, 1.0f);
        float reg_l = R / npf, cls_l = C / npf, obj_l = O / npf;
        out[0] = 5.0f * reg_l + obj_l + cls_l;
        out[1] = reg_l;
        out[2] = obj_l;
        out[3] = cls_l;
    }
}

extern "C" void kernel_launch(void* const* d_in, const int* in_sizes, int n_in,
                              void* d_out, int out_size, void* d_ws, size_t ws_size,
                              hipStream_t stream) {
    const float* p3c = (const float*)d_in[0];
    const float* p3r = (const float*)d_in[1];
    const float* p3o = (const float*)d_in[2];
    const float* p4c = (const float*)d_in[3];
    const float* p4r = (const float*)d_in[4];
    const float* p4o = (const float*)d_in[5];
    const float* p5c = (const float*)d_in[6];
    const float* p5r = (const float*)d_in[7];
    const float* p5o = (const float*)d_in[8];
    const float* targets = (const float*)d_in[9];

    char* ws = (char*)d_ws;
    unsigned int* bits = (unsigned int*)ws;               // B*264 u32, 33792 B
    float4* partials = (float4*)(ws + BITS_BYTES);        // 1600 float4

    hipMemsetAsync(bits, 0, BITS_BYTES, stream);

    fused_kernel<<<B * T, 64, 0, stream>>>(p3c, p3r, p4c, p4r, p5c, p5r,
                                           p3o, p4o, p5o, targets,
                                           bits, partials);
    finalize_kernel<<<1, 256, 0, stream>>>(partials, (float*)d_out);
}

// Round 4
// 139.496 us; speedup vs baseline: 2.0483x; 1.0651x over previous
//
#include <hip/hip_runtime.h>
#include <math.h>

#define B 32
#define T 50
#define KK 10
#define NC 80
#define A_TOT 8400
#define EPSF 1e-7f
#define IOU_THR 0.1f

#define WORDS_PER_B 264           // ceil(8400/32)=263, padded to 264
#define BITS_BYTES (B * WORDS_PER_B * 4)

__device__ __forceinline__ float softplus_bce0(float x) {
    // BCEWithLogits(x, 0) = max(x,0) + log1p(exp(-|x|))
    return fmaxf(x, 0.0f) + log1pf(expf(-fabsf(x)));
}

__device__ __forceinline__ void decode_level(int a, int& aa, int& W, int& HW, float& s) {
    if (a < 6400)      { aa = a;        W = 80; HW = 6400; s = 8.0f;  }
    else if (a < 8000) { aa = a - 6400; W = 40; HW = 1600; s = 16.0f; }
    else               { aa = a - 8000; W = 20; HW = 400;  s = 32.0f; }
}

__device__ __forceinline__ void csw(float& da, int& ia, float& db, int& ib) {
    // compare-swap ascending by (dist, idx)
    if (db < da || (db == da && ib < ia)) {
        float td = da; da = db; db = td;
        int ti = ia; ia = ib; ib = ti;
    }
}

// ---------------------------------------------------------------------------
// Fused kernel, one wave per (b,t):
//  1. top-10 nearest anchors via clamped 8x8 windows per level (1 cell/lane/
//     level -> 3 candidates/lane, provable superset of the true top-10),
//     exact lexicographic (dist, idx) wave merge = jax.lax.top_k semantics.
//  2. decode/IoU/CIoU/assignment; cls BCE gathered for ASSIGNED anchors only
//     (avg ~2-3 of 10 -> 3.5x fewer scattered line fetches than unrolled-10).
//  3. objectness: dense softplus over this block's slice + exactly-once
//     subtraction of assigned-anchor logits via atomicOr bit dedupe.
//  Writes one float4 partial per block; no contended atomics.
// ---------------------------------------------------------------------------
__global__ __launch_bounds__(64) void fused_kernel(
    const float* __restrict__ c3, const float* __restrict__ r3,
    const float* __restrict__ c4, const float* __restrict__ r4,
    const float* __restrict__ c5, const float* __restrict__ r5,
    const float* __restrict__ o3, const float* __restrict__ o4,
    const float* __restrict__ o5, const float* __restrict__ targets,
    unsigned int* __restrict__ bits, float4* __restrict__ partials)
{
    int bt = blockIdx.x;              // b*T + t
    int b = bt / T;
    int lane = threadIdx.x;
    const float* tg = targets + bt * 5;
    float tw = tg[2], th = tg[3];
    float tcx = tg[0] + tw * 0.5f, tcy = tg[1] + th * 0.5f;
    int tcls = (int)tg[4];

    // ---------------- top-k via 8x8 windows ----------------
    int ci = lane & 7, ri = lane >> 3;

    float d0, d1, d2; int id0, id1, id2;
    {
        // P3: s=8, 80x80
        int j0 = (int)(tcx * 0.125f), i0 = (int)(tcy * 0.125f);
        int js = min(max(j0 - 3, 0), 72), is = min(max(i0 - 3, 0), 72);
        int j = js + ci, i = is + ri;
        float dx = j * 8.0f + 4.0f - tcx, dy = i * 8.0f + 4.0f - tcy;
        d0 = sqrtf(dx * dx + dy * dy); id0 = i * 80 + j;
    }
    {
        // P4: s=16, 40x40
        int j0 = (int)(tcx * 0.0625f), i0 = (int)(tcy * 0.0625f);
        int js = min(max(j0 - 3, 0), 32), is = min(max(i0 - 3, 0), 32);
        int j = js + ci, i = is + ri;
        float dx = j * 16.0f + 8.0f - tcx, dy = i * 16.0f + 8.0f - tcy;
        d1 = sqrtf(dx * dx + dy * dy); id1 = 6400 + i * 40 + j;
    }
    {
        // P5: s=32, 20x20
        int j0 = (int)(tcx * 0.03125f), i0 = (int)(tcy * 0.03125f);
        int js = min(max(j0 - 3, 0), 12), is = min(max(i0 - 3, 0), 12);
        int j = js + ci, i = is + ri;
        float dx = j * 32.0f + 16.0f - tcx, dy = i * 32.0f + 16.0f - tcy;
        d2 = sqrtf(dx * dx + dy * dy); id2 = 8000 + i * 20 + j;
    }
    // sort the lane's 3 candidates ascending (network: (0,1)(1,2)(0,1))
    csw(d0, id0, d1, id1);
    csw(d1, id1, d2, id2);
    csw(d0, id0, d1, id1);

    // merge: 10 rounds of wave-wide lexicographic min over lane heads;
    // lane k keeps the k-th selected anchor in `a`. Anchor ids are unique.
    int a = 0;
    for (int k = 0; k < KK; ++k) {
        float bd = d0; int bid = id0;
#pragma unroll
        for (int sft = 1; sft < 64; sft <<= 1) {
            float od = __shfl_xor(bd, sft);
            int oid  = __shfl_xor(bid, sft);
            if (od < bd || (od == bd && oid < bid)) { bd = od; bid = oid; }
        }
        if (d0 == bd && id0 == bid) {   // exactly one lane (ids unique)
            d0 = d1; id0 = id1;
            d1 = d2; id1 = id2;
            d2 = INFINITY; id2 = 0x7fffffff;
        }
        if (lane == k) a = bid;
    }

    // ---------------- assignment / CIoU ----------------
    float x21 = tcx - tw * 0.5f, y21 = tcy - th * 0.5f;
    float x22 = tcx + tw * 0.5f, y22 = tcy + th * 0.5f;

    float iou = -INFINITY, ciou = 0.0f;
    bool valid = false;
    if (lane < KK) {
        int aa, W, HW; float s;
        decode_level(a, aa, W, HW, s);
        int i = aa / W, j = aa - i * W;
        const float* rb = (HW == 6400) ? r3 : (HW == 1600 ? r4 : r5);
        size_t rbase = ((size_t)b * 4) * (size_t)HW + (size_t)aa;
        float r0 = rb[rbase];
        float r1 = rb[rbase + (size_t)HW];
        float r2 = rb[rbase + 2 * (size_t)HW];
        float r3v = rb[rbase + 3 * (size_t)HW];
        float px = ((float)j + 1.0f / (1.0f + expf(-r0))) * s;
        float py = ((float)i + 1.0f / (1.0f + expf(-r1))) * s;
        float pw = expf(r2) * s;
        float ph = expf(r3v) * s;
        float x11 = px - pw * 0.5f, y11 = py - ph * 0.5f;
        float x12 = px + pw * 0.5f, y12 = py + ph * 0.5f;
        float iw = fmaxf(fminf(x12, x22) - fmaxf(x11, x21), 0.0f);
        float ih = fmaxf(fminf(y12, y22) - fmaxf(y11, y21), 0.0f);
        float inter = iw * ih;
        float a1 = (x12 - x11) * (y12 - y11);
        float a2 = (x22 - x21) * (y22 - y21);
        float uni = a1 + a2 - inter + EPSF;
        iou = inter / uni;
        valid = iou > IOU_THR;
        float cw = fmaxf(x12, x22) - fminf(x11, x21);
        float ch = fmaxf(y12, y22) - fminf(y11, y21);
        float c2 = cw * cw + ch * ch + EPSF;
        float ddx = x21 + x22 - x11 - x12;
        float ddy = y21 + y22 - y11 - y12;
        float rho2 = (ddx * ddx + ddy * ddy) * 0.25f;
        const float CPI = (float)(4.0 / (3.14159 * 3.14159));
        float dat = atanf((x22 - x21) / (y22 - y21 + EPSF))
                  - atanf((x12 - x11) / (y12 - y11 + EPSF));
        float v = CPI * dat * dat;
        float alpha = v / (1.0f - iou + v + EPSF);
        ciou = iou - (rho2 / c2 + v * alpha);
    }

    unsigned long long vmask = __ballot(valid);
    bool has_valid = (vmask != 0ull);

    // argmax over k of iou, first occurrence (lanes>=KK carry -inf)
    float bi = iou; int bl = lane;
#pragma unroll
    for (int sft = 1; sft < 64; sft <<= 1) {
        float oi = __shfl_xor(bi, sft);
        int ol  = __shfl_xor(bl, sft);
        if (oi > bi || (oi == bi && ol < bl)) { bi = oi; bl = ol; }
    }

    bool w = (lane < KK) && (has_valid ? valid : (lane == bl));
    unsigned long long wmask0 = __ballot(w);
    int npcount = __popcll(wmask0);

    // regression: sum (1 - ciou) over assigned
    float regc = w ? (1.0f - ciou) : 0.0f;
#pragma unroll
    for (int sft = 1; sft < 64; sft <<= 1) regc += __shfl_xor(regc, sft);

    // ---------------- objectness ----------------
    // obj_sum = sum_all softplus(x) - sum_{distinct assigned} x
    float osum = 0.0f;
    {
        int gt = bt * 64 + lane;               // 102400 threads total
        osum += softplus_bce0(o3[gt]);         // B*6400 = 204800
        osum += softplus_bce0(o3[gt + 102400]);
        if (gt < 51200) osum += softplus_bce0(o4[gt]);   // B*1600
        if (gt < 12800) osum += softplus_bce0(o5[gt]);   // B*400
    }
    if (w) {
        unsigned int bit = 1u << (a & 31);
        unsigned int old = atomicOr(&bits[b * WORDS_PER_B + (a >> 5)], bit);
        if (!(old & bit)) {                    // exactly-once per (b, anchor)
            int aa, W, HW; float s;
            decode_level(a, aa, W, HW, s);
            const float* ob = (HW == 6400) ? o3 : (HW == 1600 ? o4 : o5);
            osum -= ob[(size_t)b * HW + aa];
        }
    }
#pragma unroll
    for (int sft = 1; sft < 64; sft <<= 1) osum += __shfl_xor(osum, sft);

    // ---------------- classification ----------------
    // sum_c bce(x_c, onehot) = sum_c softplus(x_c) - x_true, gathered only
    // for assigned anchors (wave-uniform mask loop, avg ~2-3 iterations).
    float csum = 0.0f;
    unsigned long long wmask = wmask0;       // wave-uniform
    while (wmask) {
        int k = __ffsll(wmask) - 1;
        wmask &= wmask - 1;
        int ak = __shfl(a, k);
        int aak, Wk, HWk; float sk;
        decode_level(ak, aak, Wk, HWk, sk);
        const float* cb = (HWk == 6400) ? c3 : (HWk == 1600 ? c4 : c5);
        size_t cbase = ((size_t)b * NC) * (size_t)HWk + (size_t)aak;
        csum += softplus_bce0(cb[cbase + (size_t)lane * HWk]);
        if (lane < NC - 64)
            csum += softplus_bce0(cb[cbase + (size_t)(64 + lane) * HWk]);
        if (lane == 0)
            csum -= cb[cbase + (size_t)tcls * HWk];
    }
#pragma unroll
    for (int sft = 1; sft < 64; sft <<= 1) csum += __shfl_xor(csum, sft);

    if (lane == 0)
        partials[bt] = make_float4(regc, csum, (float)npcount, osum);
}

// ---------------------------------------------------------------------------
// Finalize: reduce 1600 float4 partials -> [total, reg_l, obj_l, cls_l]
// ---------------------------------------------------------------------------
__global__ __launch_bounds__(256) void finalize_kernel(
    const float4* __restrict__ partials, float* __restrict__ out)
{
    int tid = threadIdx.x;
    float reg = 0.0f, cls = 0.0f, np = 0.0f, obj = 0.0f;
    for (int i = tid; i < B * T; i += 256) {
        float4 p = partials[i];
        reg += p.x; cls += p.y; np += p.z; obj += p.w;
    }
#pragma unroll
    for (int sft = 1; sft < 64; sft <<= 1) {
        reg += __shfl_xor(reg, sft);
        cls += __shfl_xor(cls, sft);
        np  += __shfl_xor(np, sft);
        obj += __shfl_xor(obj, sft);
    }
    __shared__ float sred[4][4];
    int wv = tid >> 6;
    if ((tid & 63) == 0) {
        sred[wv][0] = reg; sred[wv][1] = cls; sred[wv][2] = np; sred[wv][3] = obj;
    }
    __syncthreads();
    if (tid == 0) {
        float R = 0, C = 0, N = 0, O = 0;
        for (int i = 0; i < 4; ++i) {
            R += sred[i][0]; C += sred[i][1]; N += sred[i][2]; O += sred[i][3];
        }
        float npf = fmaxf(N, 1.0f);
        float reg_l = R / npf, cls_l = C / npf, obj_l = O / npf;
        out[0] = 5.0f * reg_l + obj_l + cls_l;
        out[1] = reg_l;
        out[2] = obj_l;
        out[3] = cls_l;
    }
}

extern "C" void kernel_launch(void* const* d_in, const int* in_sizes, int n_in,
                              void* d_out, int out_size, void* d_ws, size_t ws_size,
                              hipStream_t stream) {
    const float* p3c = (const float*)d_in[0];
    const float* p3r = (const float*)d_in[1];
    const float* p3o = (const float*)d_in[2];
    const float* p4c = (const float*)d_in[3];
    const float* p4r = (const float*)d_in[4];
    const float* p4o = (const float*)d_in[5];
    const float* p5c = (const float*)d_in[6];
    const float* p5r = (const float*)d_in[7];
    const float* p5o = (const float*)d_in[8];
    const float* targets = (const float*)d_in[9];

    char* ws = (char*)d_ws;
    unsigned int* bits = (unsigned int*)ws;               // B*264 u32, 33792 B
    float4* partials = (float4*)(ws + BITS_BYTES);        // 1600 float4

    hipMemsetAsync(bits, 0, BITS_BYTES, stream);

    fused_kernel<<<B * T, 64, 0, stream>>>(p3c, p3r, p4c, p4r, p5c, p5r,
                                           p3o, p4o, p5o, targets,
                                           bits, partials);
    finalize_kernel<<<1, 256, 0, stream>>>(partials, (float*)d_out);
}

// Round 5
// 133.526 us; speedup vs baseline: 2.1399x; 1.0447x over previous
//
#include <hip/hip_runtime.h>
#include <math.h>

#define B 32
#define T 50
#define KK 10
#define NC 80
#define A_TOT 8400
#define EPSF 1e-7f
#define IOU_THR 0.1f

#define WORDS_PER_B 264           // ceil(8400/32)=263, padded to 264
#define BITS_BYTES (B * WORDS_PER_B * 4)

__device__ __forceinline__ float softplus_bce0(float x) {
    // BCEWithLogits(x, 0) = max(x,0) + log1p(exp(-|x|))
    return fmaxf(x, 0.0f) + log1pf(expf(-fabsf(x)));
}

__device__ __forceinline__ void decode_level(int a, int& aa, int& W, int& HW, float& s) {
    if (a < 6400)      { aa = a;        W = 80; HW = 6400; s = 8.0f;  }
    else if (a < 8000) { aa = a - 6400; W = 40; HW = 1600; s = 16.0f; }
    else               { aa = a - 8000; W = 20; HW = 400;  s = 32.0f; }
}

// pack (dist, idx) into one u64: non-negative IEEE floats order as unsigned,
// low 32 bits = anchor id -> u64 compare == lexicographic (dist, idx).
__device__ __forceinline__ unsigned long long pack_key(float d, int id) {
    return ((unsigned long long)__float_as_uint(d) << 32) | (unsigned int)id;
}

__device__ __forceinline__ void cswk(unsigned long long& ka, unsigned long long& kb) {
    if (kb < ka) { unsigned long long t = ka; ka = kb; kb = t; }
}

// ---------------------------------------------------------------------------
// Fused kernel, one wave per (b,t):
//  1. top-10 nearest anchors via clamped 8x8 windows per level (superset proof
//     holds for interior targets), exact (dist, idx) u64-key wave merge
//     = jax.lax.top_k semantics.
//  2. decode/IoU/CIoU/assignment; cls BCE via flat-parallel prefetched gathers
//     over (assigned anchor, class) items -> ONE memory round trip for nw<=3.
//  3. objectness: dense softplus over this block's slice (loads issued at
//     entry) + exactly-once subtraction of assigned logits via atomicOr.
//  Writes one float4 partial per block; no contended atomics.
// ---------------------------------------------------------------------------
__global__ __launch_bounds__(64) void fused_kernel(
    const float* __restrict__ c3, const float* __restrict__ r3,
    const float* __restrict__ c4, const float* __restrict__ r4,
    const float* __restrict__ c5, const float* __restrict__ r5,
    const float* __restrict__ o3, const float* __restrict__ o4,
    const float* __restrict__ o5, const float* __restrict__ targets,
    unsigned int* __restrict__ bits, float4* __restrict__ partials)
{
    int bt = blockIdx.x;              // b*T + t
    int b = bt / T;
    int lane = threadIdx.x;

    // ---- issue obj dense loads immediately (no dependencies) ----
    int gt = bt * 64 + lane;                   // 102400 threads total
    float ov0 = o3[gt];                        // B*6400 = 204800
    float ov1 = o3[gt + 102400];
    float ov2 = (gt < 51200) ? o4[gt] : 0.0f;  // B*1600
    float ov3 = (gt < 12800) ? o5[gt] : 0.0f;  // B*400

    const float* tg = targets + bt * 5;
    float tw = tg[2], th = tg[3];
    float tcx = tg[0] + tw * 0.5f, tcy = tg[1] + th * 0.5f;
    int tcls = (int)tg[4];

    // ---------------- top-k via 8x8 windows ----------------
    int ci = lane & 7, ri = lane >> 3;

    unsigned long long k0, k1, k2;
    {
        // P3: s=8, 80x80
        int j0 = (int)(tcx * 0.125f), i0 = (int)(tcy * 0.125f);
        int js = min(max(j0 - 3, 0), 72), is = min(max(i0 - 3, 0), 72);
        int j = js + ci, i = is + ri;
        float dx = j * 8.0f + 4.0f - tcx, dy = i * 8.0f + 4.0f - tcy;
        k0 = pack_key(sqrtf(dx * dx + dy * dy), i * 80 + j);
    }
    {
        // P4: s=16, 40x40
        int j0 = (int)(tcx * 0.0625f), i0 = (int)(tcy * 0.0625f);
        int js = min(max(j0 - 3, 0), 32), is = min(max(i0 - 3, 0), 32);
        int j = js + ci, i = is + ri;
        float dx = j * 16.0f + 8.0f - tcx, dy = i * 16.0f + 8.0f - tcy;
        k1 = pack_key(sqrtf(dx * dx + dy * dy), 6400 + i * 40 + j);
    }
    {
        // P5: s=32, 20x20
        int j0 = (int)(tcx * 0.03125f), i0 = (int)(tcy * 0.03125f);
        int js = min(max(j0 - 3, 0), 12), is = min(max(i0 - 3, 0), 12);
        int j = js + ci, i = is + ri;
        float dx = j * 32.0f + 16.0f - tcx, dy = i * 32.0f + 16.0f - tcy;
        k2 = pack_key(sqrtf(dx * dx + dy * dy), 8000 + i * 20 + j);
    }
    // sort the lane's 3 candidates ascending
    cswk(k0, k1); cswk(k1, k2); cswk(k0, k1);

    // merge: 10 rounds of wave-wide u64 min over lane heads;
    // lane k keeps the k-th selected anchor in `a`. Keys are unique.
    int a = 0;
    for (int k = 0; k < KK; ++k) {
        unsigned long long bk = k0;
#pragma unroll
        for (int sft = 1; sft < 64; sft <<= 1) {
            unsigned long long ok = __shfl_xor(bk, sft);
            if (ok < bk) bk = ok;
        }
        if (k0 == bk) {                  // exactly one lane (keys unique)
            k0 = k1; k1 = k2; k2 = ~0ull;
        }
        if (lane == k) a = (int)(unsigned int)(bk & 0xffffffffull);
    }

    // ---------------- assignment / CIoU ----------------
    float x21 = tcx - tw * 0.5f, y21 = tcy - th * 0.5f;
    float x22 = tcx + tw * 0.5f, y22 = tcy + th * 0.5f;

    float iou = -INFINITY, ciou = 0.0f;
    bool valid = false;
    if (lane < KK) {
        int aa, W, HW; float s;
        decode_level(a, aa, W, HW, s);
        int i = aa / W, j = aa - i * W;
        const float* rb = (HW == 6400) ? r3 : (HW == 1600 ? r4 : r5);
        size_t rbase = ((size_t)b * 4) * (size_t)HW + (size_t)aa;
        float r0 = rb[rbase];
        float r1 = rb[rbase + (size_t)HW];
        float r2 = rb[rbase + 2 * (size_t)HW];
        float r3v = rb[rbase + 3 * (size_t)HW];
        float px = ((float)j + 1.0f / (1.0f + expf(-r0))) * s;
        float py = ((float)i + 1.0f / (1.0f + expf(-r1))) * s;
        float pw = expf(r2) * s;
        float ph = expf(r3v) * s;
        float x11 = px - pw * 0.5f, y11 = py - ph * 0.5f;
        float x12 = px + pw * 0.5f, y12 = py + ph * 0.5f;
        float iw = fmaxf(fminf(x12, x22) - fmaxf(x11, x21), 0.0f);
        float ih = fmaxf(fminf(y12, y22) - fmaxf(y11, y21), 0.0f);
        float inter = iw * ih;
        float a1 = (x12 - x11) * (y12 - y11);
        float a2 = (x22 - x21) * (y22 - y21);
        float uni = a1 + a2 - inter + EPSF;
        iou = inter / uni;
        valid = iou > IOU_THR;
        float cw = fmaxf(x12, x22) - fminf(x11, x21);
        float ch = fmaxf(y12, y22) - fminf(y11, y21);
        float c2 = cw * cw + ch * ch + EPSF;
        float ddx = x21 + x22 - x11 - x12;
        float ddy = y21 + y22 - y11 - y12;
        float rho2 = (ddx * ddx + ddy * ddy) * 0.25f;
        const float CPI = (float)(4.0 / (3.14159 * 3.14159));
        float dat = atanf((x22 - x21) / (y22 - y21 + EPSF))
                  - atanf((x12 - x11) / (y12 - y11 + EPSF));
        float v = CPI * dat * dat;
        float alpha = v / (1.0f - iou + v + EPSF);
        ciou = iou - (rho2 / c2 + v * alpha);
    }

    unsigned long long vmask = __ballot(valid);
    bool has_valid = (vmask != 0ull);

    // argmax over k of iou, first occurrence (lanes>=KK carry -inf)
    float bi = iou; int bl = lane;
#pragma unroll
    for (int sft = 1; sft < 64; sft <<= 1) {
        float oi = __shfl_xor(bi, sft);
        int ol  = __shfl_xor(bl, sft);
        if (oi > bi || (oi == bi && ol < bl)) { bi = oi; bl = ol; }
    }

    bool w = (lane < KK) && (has_valid ? valid : (lane == bl));
    unsigned long long wmask0 = __ballot(w);
    int nw = __popcll(wmask0);

    // regression: sum (1 - ciou) over assigned
    float regc = w ? (1.0f - ciou) : 0.0f;
#pragma unroll
    for (int sft = 1; sft < 64; sft <<= 1) regc += __shfl_xor(regc, sft);

    // ---- objectness dedupe atomic: issue now, consume later ----
    unsigned int oldbits = 0, bit = 0;
    if (w) {
        bit = 1u << (a & 31);
        oldbits = atomicOr(&bits[b * WORDS_PER_B + (a >> 5)], bit);
    }

    // ---- compact assigned anchor ids to LDS ----
    __shared__ int s_aid[16];
    if (w) {
        int rank = __popcll(wmask0 & ((1ull << lane) - 1ull));
        s_aid[rank] = a;
    }
    __syncthreads();
    int n_items = nw * NC;

    // ---------------- classification ----------------
    // sum over (assigned anchor, class) items of softplus(x) - (c==tcls)*x.
    // Items 0..255 (covers nw<=3) gathered with 4 parallel loads per lane.
    auto cls_ptr = [&](int item, int& c) -> const float* {
        int k = item / NC;
        c = item - k * NC;
        int ak = s_aid[k];
        int aak, Wk, HWk; float sk;
        decode_level(ak, aak, Wk, HWk, sk);
        const float* cb = (HWk == 6400) ? c3 : (HWk == 1600 ? c4 : c5);
        return cb + ((size_t)b * NC + (size_t)c) * (size_t)HWk + (size_t)aak;
    };

    bool m0 = lane < n_items;
    bool m1 = 64 + lane < n_items;
    bool m2 = 128 + lane < n_items;
    bool m3 = 192 + lane < n_items;
    int cc0 = 0, cc1 = 0, cc2 = 0, cc3 = 0;
    float v0 = 0.0f, v1 = 0.0f, v2 = 0.0f, v3 = 0.0f;
    if (m0) v0 = *cls_ptr(lane, cc0);
    if (m1) v1 = *cls_ptr(64 + lane, cc1);
    if (m2) v2 = *cls_ptr(128 + lane, cc2);
    if (m3) v3 = *cls_ptr(192 + lane, cc3);

    // compute osum softplus while cls loads are in flight
    float osum = softplus_bce0(ov0) + softplus_bce0(ov1);
    if (gt < 51200) osum += softplus_bce0(ov2);
    if (gt < 12800) osum += softplus_bce0(ov3);
    if (w && !(oldbits & bit)) {              // exactly-once per (b, anchor)
        int aa, W, HW; float s;
        decode_level(a, aa, W, HW, s);
        const float* ob = (HW == 6400) ? o3 : (HW == 1600 ? o4 : o5);
        osum -= ob[(size_t)b * HW + aa];
    }
#pragma unroll
    for (int sft = 1; sft < 64; sft <<= 1) osum += __shfl_xor(osum, sft);

    float csum = 0.0f;
    if (m0) csum += softplus_bce0(v0) - (cc0 == tcls ? v0 : 0.0f);
    if (m1) csum += softplus_bce0(v1) - (cc1 == tcls ? v1 : 0.0f);
    if (m2) csum += softplus_bce0(v2) - (cc2 == tcls ? v2 : 0.0f);
    if (m3) csum += softplus_bce0(v3) - (cc3 == tcls ? v3 : 0.0f);
    for (int base = 256; base < n_items; base += 64) {      // nw >= 4, rare
        int item = base + lane;
        if (item < n_items) {
            int c;
            float v = *cls_ptr(item, c);
            csum += softplus_bce0(v) - (c == tcls ? v : 0.0f);
        }
    }
#pragma unroll
    for (int sft = 1; sft < 64; sft <<= 1) csum += __shfl_xor(csum, sft);

    if (lane == 0)
        partials[bt] = make_float4(regc, csum, (float)nw, osum);
}

// ---------------------------------------------------------------------------
// Finalize: reduce 1600 float4 partials -> [total, reg_l, obj_l, cls_l]
// ---------------------------------------------------------------------------
__global__ __launch_bounds__(256) void finalize_kernel(
    const float4* __restrict__ partials, float* __restrict__ out)
{
    int tid = threadIdx.x;
    float reg = 0.0f, cls = 0.0f, np = 0.0f, obj = 0.0f;
    for (int i = tid; i < B * T; i += 256) {
        float4 p = partials[i];
        reg += p.x; cls += p.y; np += p.z; obj += p.w;
    }
#pragma unroll
    for (int sft = 1; sft < 64; sft <<= 1) {
        reg += __shfl_xor(reg, sft);
        cls += __shfl_xor(cls, sft);
        np  += __shfl_xor(np, sft);
        obj += __shfl_xor(obj, sft);
    }
    __shared__ float sred[4][4];
    int wv = tid >> 6;
    if ((tid & 63) == 0) {
        sred[wv][0] = reg; sred[wv][1] = cls; sred[wv][2] = np; sred[wv][3] = obj;
    }
    __syncthreads();
    if (tid == 0) {
        float R = 0, C = 0, N = 0, O = 0;
        for (int i = 0; i < 4; ++i) {
            R += sred[i][0]; C += sred[i][1]; N += sred[i][2]; O += sred[i][3];
        }
        float npf = fmaxf(N, 1.0f);
        float reg_l = R / npf, cls_l = C / npf, obj_l = O / npf;
        out[0] = 5.0f * reg_l + obj_l + cls_l;
        out[1] = reg_l;
        out[2] = obj_l;
        out[3] = cls_l;
    }
}

extern "C" void kernel_launch(void* const* d_in, const int* in_sizes, int n_in,
                              void* d_out, int out_size, void* d_ws, size_t ws_size,
                              hipStream_t stream) {
    const float* p3c = (const float*)d_in[0];
    const float* p3r = (const float*)d_in[1];
    const float* p3o = (const float*)d_in[2];
    const float* p4c = (const float*)d_in[3];
    const float* p4r = (const float*)d_in[4];
    const float* p4o = (const float*)d_in[5];
    const float* p5c = (const float*)d_in[6];
    const float* p5r = (const float*)d_in[7];
    const float* p5o = (const float*)d_in[8];
    const float* targets = (const float*)d_in[9];

    char* ws = (char*)d_ws;
    unsigned int* bits = (unsigned int*)ws;               // B*264 u32, 33792 B
    float4* partials = (float4*)(ws + BITS_BYTES);        // 1600 float4

    hipMemsetAsync(bits, 0, BITS_BYTES, stream);

    fused_kernel<<<B * T, 64, 0, stream>>>(p3c, p3r, p4c, p4r, p5c, p5r,
                                           p3o, p4o, p5o, targets,
                                           bits, partials);
    finalize_kernel<<<1, 256, 0, stream>>>(partials, (float*)d_out);
}